// Round 3
// baseline (261.933 us; speedup 1.0000x reference)
//
#include <hip/hip_runtime.h>
#include <stdint.h>

typedef __bf16 bf16x8_t __attribute__((ext_vector_type(8)));
typedef float f32x4_t __attribute__((ext_vector_type(4)));

__device__ __forceinline__ uint32_t f32_to_bf16_bits(float f) {
    union { float f; uint32_t u; } v; v.f = f;
    return (v.u + 0x7FFFu + ((v.u >> 16) & 1u)) >> 16;   // RNE, finite inputs
}

__device__ __forceinline__ float bf16_bits_to_f32(uint32_t b) {
    union { uint32_t u; float f; } v; v.u = b << 16;
    return v.f;
}

// ---------------------------------------------------------------------------
// Merged prep (unchanged):
//  blocks [0,4096):    Ae[n,r]=cos(pi*2r(2n+1)/8192), Ao[n,r]=cos(pi*(2r+1)(2n+1)/8192)
//  blocks [4096,12288): Xe[q,r]=bf16(x[q,2r]), Xo[q,r]=bf16(x[q,2r+1])
// ---------------------------------------------------------------------------
__global__ void prep_kernel(const float* __restrict__ X,
                            unsigned short* __restrict__ Ae,
                            unsigned short* __restrict__ Ao,
                            unsigned short* __restrict__ Xe,
                            unsigned short* __restrict__ Xo) {
    if (blockIdx.x < 4096) {
        const int idx = blockIdx.x * 256 + threadIdx.x;   // 0..1M-1
        const int sel = idx >> 19;                        // 0=even, 1=odd matrix
        const int e   = idx & ((1 << 19) - 1);
        const int n   = e >> 8;                           // 0..2047
        const int c0  = (e & 255) << 3;                   // col start
        const uint32_t tn = (uint32_t)(2 * n + 1);
        unsigned short* dst = sel ? Ao : Ae;
        uint32_t packed[4];
#pragma unroll
        for (int jj = 0; jj < 4; ++jj) {
            uint32_t cA = (uint32_t)(c0 + 2 * jj);
            uint32_t cB = cA + 1;
            uint32_t r0 = ((2u * cA + (uint32_t)sel) * tn) & 16383u;
            uint32_t r1 = ((2u * cB + (uint32_t)sel) * tn) & 16383u;
            float v0 = __cosf((float)r0 * 3.8349519697141e-4f);   // pi/8192
            float v1 = __cosf((float)r1 * 3.8349519697141e-4f);
            packed[jj] = f32_to_bf16_bits(v0) | (f32_to_bf16_bits(v1) << 16);
        }
        *(uint4*)(dst + (size_t)n * 2048 + c0) = make_uint4(packed[0], packed[1], packed[2], packed[3]);
    } else {
        const int idx = (blockIdx.x - 4096) * 256 + threadIdx.x;   // 0..2M-1
        const int q   = idx >> 9;
        const int p0  = (idx & 511) << 3;
        const float4* src = (const float4*)(X + (size_t)q * 4096 + p0);
        float4 a = src[0];
        float4 b = src[1];
        uint2 ev, od;
        ev.x = f32_to_bf16_bits(a.x) | (f32_to_bf16_bits(a.z) << 16);
        ev.y = f32_to_bf16_bits(b.x) | (f32_to_bf16_bits(b.z) << 16);
        od.x = f32_to_bf16_bits(a.y) | (f32_to_bf16_bits(a.w) << 16);
        od.y = f32_to_bf16_bits(b.y) | (f32_to_bf16_bits(b.w) << 16);
        *(uint2*)(Xe + (size_t)q * 2048 + (p0 >> 1)) = ev;
        *(uint2*)(Xo + (size_t)q * 2048 + (p0 >> 1)) = od;
    }
}

// ---------------------------------------------------------------------------
// Single-parity 256x256 GEMM (parity = blockIdx.z), BK=64, 512 threads =
// 8 waves (2M x 4N), per-wave 128x64 (8x4 frags of 16x16x32 bf16).
//
// Rationale (round-2 post-mortem): at 128-row tiles the kernel is at the
// L2-BW break-even (64 FLOP/staged-byte vs ~60 needed); 256^2 doubles
// FLOP/byte to 128, making staging hideable. Splitting the butterfly into
// separate streaming passes is what frees the register budget for a
// single-parity 256^2 accumulator (128 VGPR).
//
// Schedule: round-2's proven 2-phase loop — STAGE(t+1) issued first,
// compute tile t (no mid barriers), one vmcnt(0)+s_barrier per tile.
// LDS: 2 x (A 256x64 + B 256x64) bf16 = 128 KB, chunk-XOR swizzle:
// phys slot s of row r holds logical k-chunk g = s ^ (r&7); staging
// pre-swizzles the global source address (global_load_lds dest must stay
// lane-linear), fragment reads XOR on the slot. 0 bank conflicts (verified).
// C written as bf16 [2048][4096].
// ---------------------------------------------------------------------------
#define GLL(gp, lp) __builtin_amdgcn_global_load_lds( \
        (const __attribute__((address_space(1))) uint32_t*)(gp), \
        (__attribute__((address_space(3))) uint32_t*)(lp), 16, 0, 0)

__global__ __launch_bounds__(512, 2)
void gemm256_kernel(const unsigned short* __restrict__ Ae,
                    const unsigned short* __restrict__ Ao,
                    const unsigned short* __restrict__ Be,
                    const unsigned short* __restrict__ Bo,
                    unsigned short* __restrict__ Ce,
                    unsigned short* __restrict__ Co) {
    constexpr int KD = 2048;
    // 2 buffers x (A 16384 + B 16384 shorts) = 128 KB
    __shared__ __attribute__((aligned(16))) unsigned short smem[2 * 32768];

    const int tid  = threadIdx.x;
    const int wave = tid >> 6;
    const int lane = tid & 63;
    const int wm   = wave >> 2;     // 0..1 (M: cosine dim, 128 rows each)
    const int wn   = wave & 3;      // 0..3 (N: data dim, 64 cols each)

    const int tile_m = blockIdx.y << 8;   // cosine rows: [0,2048), 8 tiles
    const int tile_c = blockIdx.x << 8;   // data rows (= C cols): [0,4096), 16 tiles
    const int par    = blockIdx.z;

    const unsigned short* gA = (par ? Ao : Ae) + (size_t)tile_m * KD;
    const unsigned short* gB = (par ? Bo : Be) + (size_t)tile_c * KD;
    unsigned short*       gC = par ? Co : Ce;

    f32x4_t acc[8][4];
#pragma unroll
    for (int i = 0; i < 8; ++i)
#pragma unroll
        for (int j = 0; j < 4; ++j)
            acc[i][j] = (f32x4_t){0.f, 0.f, 0.f, 0.f};

    // Staging: per panel (A or B) 2048 chunks of 16B over 256 rows x 8 slots.
    // Thread covers chunks c = tid + 512k (k<4).
    //   per-lane global src (swizzled): row = c>>3, g = (c&7)^(row&7)
    //   LDS dest: linear chunk c (lane-contiguous per wave-instruction)
    int src_off[4], lds_off[4];
#pragma unroll
    for (int k = 0; k < 4; ++k) {
        const int c   = tid + (k << 9);
        const int row = c >> 3;
        const int g   = (c & 7) ^ (row & 7);
        src_off[k] = row * KD + (g << 3);
        lds_off[k] = c << 3;   // shorts
    }

    // Fragment read addressing (swizzled).
    const int frow = lane & 15;
    const int sw   = frow & 7;
    const int gq   = lane >> 4;
    const int aRowB = (wm * 128 + frow) * 64;   // A LDS [256][64] shorts
    const int bRowB = (wn * 64  + frow) * 64;   // B LDS [256][64] shorts

#define STAGE_TILE(buf, kadv) do {                                            \
    _Pragma("unroll")                                                         \
    for (int k_ = 0; k_ < 4; ++k_)                                            \
        GLL(gA + (kadv) + src_off[k_], (buf) + lds_off[k_]);                  \
    _Pragma("unroll")                                                         \
    for (int k_ = 0; k_ < 4; ++k_)                                            \
        GLL(gB + (kadv) + src_off[k_], (buf) + 16384 + lds_off[k_]);          \
} while (0)

#define COMPUTE_TILE(buf) do {                                                \
    _Pragma("unroll")                                                         \
    for (int kh_ = 0; kh_ < 2; ++kh_) {                                       \
        const int so_ = (((kh_ << 2) + gq) ^ sw) << 3;                        \
        bf16x8_t af_[8], bf_[4];                                              \
        _Pragma("unroll")                                                     \
        for (int i_ = 0; i_ < 8; ++i_) af_[i_] = *(const bf16x8_t*)((buf) + aRowB + i_ * 1024 + so_); \
        _Pragma("unroll")                                                     \
        for (int j_ = 0; j_ < 4; ++j_) bf_[j_] = *(const bf16x8_t*)((buf) + 16384 + bRowB + j_ * 1024 + so_); \
        __builtin_amdgcn_s_setprio(1);                                        \
        _Pragma("unroll")                                                     \
        for (int i_ = 0; i_ < 8; ++i_)                                        \
            _Pragma("unroll")                                                 \
            for (int j_ = 0; j_ < 4; ++j_)                                    \
                acc[i_][j_] = __builtin_amdgcn_mfma_f32_16x16x32_bf16(af_[i_], bf_[j_], acc[i_][j_], 0, 0, 0); \
        __builtin_amdgcn_s_setprio(0);                                        \
    }                                                                         \
} while (0)

#define TILE_SYNC() do {                                                      \
    asm volatile("s_waitcnt vmcnt(0)" ::: "memory");                          \
    __builtin_amdgcn_s_barrier();                                             \
    asm volatile("" ::: "memory");                                            \
} while (0)

    // Prologue: stage tile 0 into buf0.
    STAGE_TILE(smem, 0);
    TILE_SYNC();

    int co = 0;   // compute-buffer offset (shorts); staging targets co^32768
#pragma unroll 1
    for (int t = 0; t < 31; ++t) {
        STAGE_TILE(smem + (co ^ 32768), (size_t)(t + 1) << 6);
        COMPUTE_TILE(smem + co);
        TILE_SYNC();
        co ^= 32768;
    }
    COMPUTE_TILE(smem + co);   // tile 31: nothing left to stage

#undef STAGE_TILE
#undef COMPUTE_TILE
#undef TILE_SYNC

    // C/D map: col = lane&15 (data dim), row = (lane>>4)*4 + reg (cos dim)
    const int orow = tile_m + wm * 128 + ((lane >> 4) << 2);
    const int ocol = tile_c + wn * 64 + (lane & 15);
#pragma unroll
    for (int i = 0; i < 8; ++i)
#pragma unroll
        for (int j = 0; j < 4; ++j)
#pragma unroll
            for (int r = 0; r < 4; ++r) {
                const int m = orow + i * 16 + r;
                const int w = ocol + j * 16;
                gC[(size_t)m * 4096 + w] = (unsigned short)f32_to_bf16_bits(acc[i][j][r]);
            }
}

// ---------------------------------------------------------------------------
// Butterfly 1: Ce,Co [2048][4096] bf16 -> Te,To [4096][2048] bf16.
//   T[m][w]      = e+o ; T[4095-m][w] = e-o ; column parity w -> Te/To[w>>1].
// Grid 2048 blocks x 256 threads; thread covers 16 consecutive cols.
// ---------------------------------------------------------------------------
__global__ void bfly1_kernel(const unsigned short* __restrict__ Ce,
                             const unsigned short* __restrict__ Co,
                             unsigned short* __restrict__ Te,
                             unsigned short* __restrict__ To) {
    const int m  = blockIdx.x;
    const int c0 = threadIdx.x << 4;
    const uint4 e0 = *(const uint4*)(Ce + (size_t)m * 4096 + c0);
    const uint4 e1 = *(const uint4*)(Ce + (size_t)m * 4096 + c0 + 8);
    const uint4 o0 = *(const uint4*)(Co + (size_t)m * 4096 + c0);
    const uint4 o1 = *(const uint4*)(Co + (size_t)m * 4096 + c0 + 8);
    const uint32_t eu[8] = {e0.x, e0.y, e0.z, e0.w, e1.x, e1.y, e1.z, e1.w};
    const uint32_t ou[8] = {o0.x, o0.y, o0.z, o0.w, o1.x, o1.y, o1.z, o1.w};
    uint32_t se[4], so_[4], de[4], do_[4];   // packed pairs: even cols / odd cols
#pragma unroll
    for (int u = 0; u < 4; ++u) {
        // words 2u, 2u+1 hold cols c0+4u .. c0+4u+3 (lo16 = even col, hi16 = odd)
        float eA = bf16_bits_to_f32(eu[2*u] & 0xFFFF),  oA = bf16_bits_to_f32(ou[2*u] & 0xFFFF);
        float eB = bf16_bits_to_f32(eu[2*u] >> 16),     oB = bf16_bits_to_f32(ou[2*u] >> 16);
        float eC = bf16_bits_to_f32(eu[2*u+1] & 0xFFFF),oC = bf16_bits_to_f32(ou[2*u+1] & 0xFFFF);
        float eD = bf16_bits_to_f32(eu[2*u+1] >> 16),   oD = bf16_bits_to_f32(ou[2*u+1] >> 16);
        se[u]  = f32_to_bf16_bits(eA + oA) | (f32_to_bf16_bits(eC + oC) << 16);
        so_[u] = f32_to_bf16_bits(eB + oB) | (f32_to_bf16_bits(eD + oD) << 16);
        de[u]  = f32_to_bf16_bits(eA - oA) | (f32_to_bf16_bits(eC - oC) << 16);
        do_[u] = f32_to_bf16_bits(eB - oB) | (f32_to_bf16_bits(eD - oD) << 16);
    }
    const size_t rs = (size_t)m * 2048 + (c0 >> 1);
    const size_t rd = (size_t)(4095 - m) * 2048 + (c0 >> 1);
    *(uint4*)(Te + rs) = make_uint4(se[0], se[1], se[2], se[3]);
    *(uint4*)(To + rs) = make_uint4(so_[0], so_[1], so_[2], so_[3]);
    *(uint4*)(Te + rd) = make_uint4(de[0], de[1], de[2], de[3]);
    *(uint4*)(To + rd) = make_uint4(do_[0], do_[1], do_[2], do_[3]);
}

// ---------------------------------------------------------------------------
// Butterfly 2: Ce2,Co2 [2048][4096] bf16 -> out [4096][4096] f32.
//   out[m][w] = e+o ; out[4095-m][w] = e-o.
// ---------------------------------------------------------------------------
__global__ void bfly2_kernel(const unsigned short* __restrict__ Ce,
                             const unsigned short* __restrict__ Co,
                             float* __restrict__ out) {
    const int m  = blockIdx.x;
    const int c0 = threadIdx.x << 4;
    const uint4 e0 = *(const uint4*)(Ce + (size_t)m * 4096 + c0);
    const uint4 e1 = *(const uint4*)(Ce + (size_t)m * 4096 + c0 + 8);
    const uint4 o0 = *(const uint4*)(Co + (size_t)m * 4096 + c0);
    const uint4 o1 = *(const uint4*)(Co + (size_t)m * 4096 + c0 + 8);
    const uint32_t eu[8] = {e0.x, e0.y, e0.z, e0.w, e1.x, e1.y, e1.z, e1.w};
    const uint32_t ou[8] = {o0.x, o0.y, o0.z, o0.w, o1.x, o1.y, o1.z, o1.w};
    float s[16], d[16];
#pragma unroll
    for (int u = 0; u < 8; ++u) {
        const float eL = bf16_bits_to_f32(eu[u] & 0xFFFF), oL = bf16_bits_to_f32(ou[u] & 0xFFFF);
        const float eH = bf16_bits_to_f32(eu[u] >> 16),    oH = bf16_bits_to_f32(ou[u] >> 16);
        s[2*u] = eL + oL; s[2*u+1] = eH + oH;
        d[2*u] = eL - oL; d[2*u+1] = eH - oH;
    }
    float* ps = out + (size_t)m * 4096 + c0;
    float* pd = out + (size_t)(4095 - m) * 4096 + c0;
#pragma unroll
    for (int u = 0; u < 4; ++u) {
        *(float4*)(ps + 4 * u) = make_float4(s[4*u], s[4*u+1], s[4*u+2], s[4*u+3]);
        *(float4*)(pd + 4 * u) = make_float4(d[4*u], d[4*u+1], d[4*u+2], d[4*u+3]);
    }
}

// ---------------------------------------------------------------------------
// Pipeline:
//   prep:   Ae,Ao (cosine tables) + Xe,Xo (deinterleaved bf16 x)
//   gemm1:  z-parity: Ae x Xe^T -> C1e ; Ao x Xo^T -> C1o   (bf16)
//   bfly1:  C1e,C1o -> Te,To  (row butterfly + column-parity split)
//   gemm2:  Ae x Te^T -> C2e ; Ao x To^T -> C2o             (bf16)
//   bfly2:  C2e,C2o -> out (f32)
// ws (80 MB): Ae[0,8) Ao[8,16) | Xe[16,32) Xo[32,48) -> reused as Te,To
//             | C1e[48,64) C1o[64,80) -> reused as C2e,C2o
// ---------------------------------------------------------------------------
extern "C" void kernel_launch(void* const* d_in, const int* in_sizes, int n_in,
                              void* d_out, int out_size, void* d_ws, size_t ws_size,
                              hipStream_t stream) {
    const float* x = (const float*)d_in[0];
    char* ws = (char*)d_ws;
    const size_t MB = 1024 * 1024;
    unsigned short* Ae = (unsigned short*)(ws);
    unsigned short* Ao = (unsigned short*)(ws + 8 * MB);
    unsigned short* Xe = (unsigned short*)(ws + 16 * MB);   // later Te
    unsigned short* Xo = (unsigned short*)(ws + 32 * MB);   // later To
    unsigned short* C1e = (unsigned short*)(ws + 48 * MB);  // later C2e
    unsigned short* C1o = (unsigned short*)(ws + 64 * MB);  // later C2o
    float* out = (float*)d_out;

    prep_kernel<<<12288, 256, 0, stream>>>(x, Ae, Ao, Xe, Xo);

    dim3 ggrid(16, 8, 2);
    gemm256_kernel<<<ggrid, 512, 0, stream>>>(Ae, Ao, Xe, Xo, C1e, C1o);
    bfly1_kernel<<<2048, 256, 0, stream>>>(C1e, C1o, /*Te=*/Xe, /*To=*/Xo);
    gemm256_kernel<<<ggrid, 512, 0, stream>>>(Ae, Ao, /*Te=*/Xe, /*To=*/Xo, C1e, C1o);
    bfly2_kernel<<<2048, 256, 0, stream>>>(C1e, C1o, out);
}